// Round 14
// baseline (146.984 us; speedup 1.0000x reference)
//
#include <hip/hip_runtime.h>

#define D 128
#define SCAN_CHUNK 4096    // elements per scan block (old tier-B path)
#define PART_ELEMS 4096    // incidences per partition block (1024 thr x 4)
#define MAXB 2048          // max buckets per direction (LDS arrays)

typedef __attribute__((ext_vector_type(8))) short   bf16x8;
typedef __attribute__((ext_vector_type(4))) float   f32x4;
typedef __attribute__((ext_vector_type(4))) unsigned short us4;
typedef __attribute__((ext_vector_type(8))) unsigned short us8;

#define LDSP (D + 8)       // bf16 LDS row pitch: 136 elems = 272 B (2-way max)

__device__ __forceinline__ unsigned short f2bf(float x) {
    union { float f; unsigned u; } v; v.f = x;
    unsigned r = v.u + 0x7fffu + ((v.u >> 16) & 1u);   // round-to-nearest-even
    return (unsigned short)(r >> 16);
}
__device__ __forceinline__ float bf2f(unsigned short u) {
    union { unsigned u; float f; } v; v.u = ((unsigned)u) << 16; return v.f;
}

// ---------------------------------------------------------------------------
// f32 -> bf16 bulk convert
// ---------------------------------------------------------------------------
__global__ void __launch_bounds__(256) cvt_f32_bf16_kernel(
    const float* __restrict__ in, unsigned short* __restrict__ out, int n4)
{
    int stride = gridDim.x * 256;
    for (int i = blockIdx.x * 256 + threadIdx.x; i < n4; i += stride) {
        float4 v = *reinterpret_cast<const float4*>(in + (size_t)i * 4);
        us4 b = { f2bf(v.x), f2bf(v.y), f2bf(v.z), f2bf(v.w) };
        *reinterpret_cast<us4*>(out + (size_t)i * 4) = b;
    }
}

// ===========================================================================
// Bucketed CSR builder (tier A) — atomic-free, memset-free variant.
// ===========================================================================

__global__ void __launch_bounds__(1024) part_hist_kernel(
    const int* __restrict__ node_idx, const int* __restrict__ edge_idx,
    int* __restrict__ blockBaseE, int* __restrict__ blockBaseV,
    int NBE, int NBV, int I)
{
    __shared__ int hE[MAXB];
    __shared__ int hV[MAXB];
    const int tid = threadIdx.x, blk = blockIdx.x;
    for (int k = tid; k < NBE; k += 1024) hE[k] = 0;
    for (int k = tid; k < NBV; k += 1024) hV[k] = 0;
    __syncthreads();
    const int base = blk * PART_ELEMS;
    #pragma unroll
    for (int j = 0; j < PART_ELEMS / 1024; ++j) {
        int i = base + j * 1024 + tid;
        if (i < I) {
            atomicAdd(&hE[edge_idx[i] >> 6], 1);
            atomicAdd(&hV[node_idx[i] >> 7], 1);
        }
    }
    __syncthreads();
    for (int k = tid; k < NBE; k += 1024)
        blockBaseE[(size_t)blk * NBE + k] = hE[k];
    for (int k = tid; k < NBV; k += 1024)
        blockBaseV[(size_t)blk * NBV + k] = hV[k];
}

// block 0: edge dir, block 1: node dir. Per bucket (one thread each):
// walk HB blocks converting counts -> exclusive block prefix (in place),
// then LDS-scan bucket totals -> bktBase (exclusive, +total at [n]).
__global__ void __launch_bounds__(1024) bucket_scan_kernel(
    int* __restrict__ blockBaseE, int* __restrict__ bktBaseE, int nE,
    int* __restrict__ blockBaseV, int* __restrict__ bktBaseV, int nV,
    int HB)
{
    __shared__ int lds[1024];
    int* blockBase = blockIdx.x ? blockBaseV : blockBaseE;
    int* bktBase   = blockIdx.x ? bktBaseV : bktBaseE;
    const int n    = blockIdx.x ? nV : nE;
    const int tid  = threadIdx.x;
    int total = 0;
    if (tid < n) {
        size_t idx = tid;
        int blk = 0;
        for (; blk + 4 <= HB; blk += 4) {
            int t0 = blockBase[idx];
            int t1 = blockBase[idx + (size_t)n];
            int t2 = blockBase[idx + (size_t)2 * n];
            int t3 = blockBase[idx + (size_t)3 * n];
            blockBase[idx] = total;
            blockBase[idx + (size_t)n] = total + t0;
            blockBase[idx + (size_t)2 * n] = total + t0 + t1;
            blockBase[idx + (size_t)3 * n] = total + t0 + t1 + t2;
            total += t0 + t1 + t2 + t3;
            idx += (size_t)4 * n;
        }
        for (; blk < HB; ++blk) {
            int t = blockBase[idx];
            blockBase[idx] = total;
            total += t;
            idx += n;
        }
    }
    lds[tid] = (tid < n) ? total : 0;
    __syncthreads();
    for (int o = 1; o < 1024; o <<= 1) {
        int t = lds[tid];
        int u = (tid >= o) ? lds[tid - o] : 0;
        __syncthreads();
        lds[tid] = t + u;
        __syncthreads();
    }
    if (tid < n) bktBase[tid] = lds[tid] - total;   // exclusive
    if (tid == 0) bktBase[n] = lds[1023];           // total
}

__global__ void __launch_bounds__(1024) part_scatter_kernel(
    const int* __restrict__ node_idx, const int* __restrict__ edge_idx,
    const int* __restrict__ bktBaseE, const int* __restrict__ bktBaseV,
    const int* __restrict__ blockBaseE, const int* __restrict__ blockBaseV,
    int* __restrict__ pairsE, int* __restrict__ pairsV,
    int NBE, int NBV, int I)
{
    __shared__ int bE[MAXB];
    __shared__ int bV[MAXB];
    const int tid = threadIdx.x, blk = blockIdx.x;
    for (int k = tid; k < NBE; k += 1024)
        bE[k] = bktBaseE[k] + blockBaseE[(size_t)blk * NBE + k];
    for (int k = tid; k < NBV; k += 1024)
        bV[k] = bktBaseV[k] + blockBaseV[(size_t)blk * NBV + k];
    __syncthreads();
    const int base = blk * PART_ELEMS;
    #pragma unroll
    for (int j = 0; j < PART_ELEMS / 1024; ++j) {
        int i = base + j * 1024 + tid;
        if (i < I) {
            int ev = edge_idx[i], nv = node_idx[i];
            int pE = atomicAdd(&bE[ev >> 6], 1);
            pairsE[pE] = (nv << 6) | (ev & 63);
            int pV = atomicAdd(&bV[nv >> 7], 1);
            pairsV[pV] = (ev << 7) | (nv & 127);
        }
    }
}

// K4: per-bucket bin histogram -> scan -> sorted payloads + pre-gathered weights
__global__ void __launch_bounds__(256) bin_csr_kernel(
    const int* __restrict__ pairsE, const int* __restrict__ pairsV,
    const int* __restrict__ bktBaseE, const int* __restrict__ bktBaseV,
    int* __restrict__ offE, int* __restrict__ cntE,
    int* __restrict__ offV, int* __restrict__ cntV,
    int* __restrict__ sorted_n, int* __restrict__ sorted_e,
    const float* __restrict__ vrw, const float* __restrict__ erw,
    float* __restrict__ sorted_wn, float* __restrict__ sorted_we,
    int NBE, int NBV, int E, int V)
{
    __shared__ int cnt[128], off[128], cur[128];
    const int tid = threadIdx.x;
    const int blk = blockIdx.x;
    if (blk < NBE) {
        const int k = blk, lo = bktBaseE[k], hi = bktBaseE[k + 1];
        if (tid < 64) cnt[tid] = 0;
        __syncthreads();
        for (int i = lo + tid; i < hi; i += 256)
            atomicAdd(&cnt[pairsE[i] & 63], 1);
        __syncthreads();
        if (tid < 64) off[tid] = cnt[tid];
        __syncthreads();
        for (int o = 1; o < 64; o <<= 1) {
            int t = 0;
            if (tid < 64) { t = off[tid]; if (tid >= o) t += off[tid - o]; }
            __syncthreads();
            if (tid < 64) off[tid] = t;
            __syncthreads();
        }
        if (tid < 64) {
            int excl = off[tid] - cnt[tid];
            int bin = k * 64 + tid;
            if (bin < E) { cntE[bin] = cnt[tid]; offE[bin] = lo + excl; }
            cur[tid] = 0;
            off[tid] = excl;
        }
        __syncthreads();
        for (int i = lo + tid; i < hi; i += 256) {
            int w = pairsE[i];
            int b = w & 63;
            int r = atomicAdd(&cur[b], 1);
            int src = w >> 6;
            int pos = lo + off[b] + r;
            sorted_n[pos] = src;
            sorted_wn[pos] = vrw[src];
        }
    } else {
        const int k = blk - NBE, lo = bktBaseV[k], hi = bktBaseV[k + 1];
        if (tid < 128) cnt[tid] = 0;
        __syncthreads();
        for (int i = lo + tid; i < hi; i += 256)
            atomicAdd(&cnt[pairsV[i] & 127], 1);
        __syncthreads();
        if (tid < 128) off[tid] = cnt[tid];
        __syncthreads();
        for (int o = 1; o < 128; o <<= 1) {
            int t = 0;
            if (tid < 128) { t = off[tid]; if (tid >= o) t += off[tid - o]; }
            __syncthreads();
            if (tid < 128) off[tid] = t;
            __syncthreads();
        }
        if (tid < 128) {
            int excl = off[tid] - cnt[tid];
            int bin = k * 128 + tid;
            if (bin < V) { cntV[bin] = cnt[tid]; offV[bin] = lo + excl; }
            cur[tid] = 0;
            off[tid] = excl;
        }
        __syncthreads();
        for (int i = lo + tid; i < hi; i += 256) {
            int w = pairsV[i];
            int b = w & 127;
            int r = atomicAdd(&cur[b], 1);
            int src = w >> 7;
            int pos = lo + off[b] + r;
            sorted_e[pos] = src;
            sorted_we[pos] = erw[src];
        }
    }
}

// ===========================================================================
// Old CSR builder kernels (tier B fallback) + atomic scatter (tier C)
// ===========================================================================
__global__ void __launch_bounds__(256) scatter_kernel(
    const float* __restrict__ feat, const float* __restrict__ w_num,
    const float* __restrict__ w_den, const int* __restrict__ src_idx,
    const int* __restrict__ dst_idx, float* __restrict__ acc, int n_inc)
{
    int gid = blockIdx.x * 256 + threadIdx.x;
    int inc = gid >> 5;
    if (inc >= n_inc) return;
    int c = (gid & 31) << 2;
    int s = src_idx[inc];
    int t = dst_idx[inc];
    float w = w_num[s] / w_den[t];
    float4 v = *reinterpret_cast<const float4*>(feat + (size_t)s * D + c);
    float* dst = acc + (size_t)t * D + c;
    atomicAdd(dst + 0, w * v.x);
    atomicAdd(dst + 1, w * v.y);
    atomicAdd(dst + 2, w * v.z);
    atomicAdd(dst + 3, w * v.w);
}

__global__ void __launch_bounds__(256) hist_rank_kernel(
    const int* __restrict__ node_idx, const int* __restrict__ edge_idx,
    int* __restrict__ cnt, int* __restrict__ rank_e, int* __restrict__ rank_v,
    int E, int n)
{
    int half = (n + 1) >> 1;
    int i = blockIdx.x * 256 + threadIdx.x;
    if (i >= half) return;
    int nv0 = node_idx[i], ev0 = edge_idx[i];
    int j = i + half;
    if (j < n) {
        int nv1 = node_idx[j], ev1 = edge_idx[j];
        int a = atomicAdd(&cnt[ev0], 1);
        int b = atomicAdd(&cnt[ev1], 1);
        int c = atomicAdd(&cnt[E + nv0], 1);
        int d = atomicAdd(&cnt[E + nv1], 1);
        rank_e[i] = a; rank_e[j] = b;
        rank_v[i] = c; rank_v[j] = d;
    } else {
        rank_e[i] = atomicAdd(&cnt[ev0], 1);
        rank_v[i] = atomicAdd(&cnt[E + nv0], 1);
    }
}

__global__ void __launch_bounds__(1024) scan_block_kernel(
    const int* __restrict__ in, int* __restrict__ out,
    int* __restrict__ blocksums, int n)
{
    __shared__ int lds[1024];
    const int tid = threadIdx.x;
    const int idx = blockIdx.x * SCAN_CHUNK + tid * 4;
    int4 v = make_int4(0, 0, 0, 0);
    if (idx + 3 < n) v = *reinterpret_cast<const int4*>(in + idx);
    else {
        if (idx + 0 < n) v.x = in[idx + 0];
        if (idx + 1 < n) v.y = in[idx + 1];
        if (idx + 2 < n) v.z = in[idx + 2];
        if (idx + 3 < n) v.w = in[idx + 3];
    }
    lds[tid] = v.x + v.y + v.z + v.w;
    __syncthreads();
    for (int off = 1; off < 1024; off <<= 1) {
        int t = lds[tid];
        int u = (tid >= off) ? lds[tid - off] : 0;
        __syncthreads();
        lds[tid] = t + u;
        __syncthreads();
    }
    int excl = tid ? lds[tid - 1] : 0;
    if (blocksums && tid == 1023) blocksums[blockIdx.x] = lds[1023];
    int4 o;
    o.x = excl;
    o.y = o.x + v.x;
    o.z = o.y + v.y;
    o.w = o.z + v.z;
    if (idx + 3 < n) *reinterpret_cast<int4*>(out + idx) = o;
    else {
        if (idx + 0 < n) out[idx + 0] = o.x;
        if (idx + 1 < n) out[idx + 1] = o.y;
        if (idx + 2 < n) out[idx + 2] = o.z;
        if (idx + 3 < n) out[idx + 3] = o.w;
    }
}

__global__ void __launch_bounds__(256) place_kernel(
    const int* __restrict__ node_idx, const int* __restrict__ edge_idx,
    const int* __restrict__ rank_e, const int* __restrict__ rank_v,
    const int* __restrict__ off, const int* __restrict__ bsum,
    int* __restrict__ sorted_n, int* __restrict__ sorted_e,
    int E, int I)
{
    int i = blockIdx.x * 256 + threadIdx.x;
    if (i >= I) return;
    int nv = node_idx[i], ev = edge_idx[i];
    sorted_n[off[ev] + bsum[ev >> 12] + rank_e[i]] = nv;
    int b2 = E + nv;
    sorted_e[off[b2] + bsum[b2 >> 12] - I + rank_v[i]] = ev;
}

// ---------------------------------------------------------------------------
// OLD gather (tier B): 32 lanes/row, f32 table.
// ---------------------------------------------------------------------------
template <int IN_BF>
__device__ __forceinline__ float4 ldrow4(const void* feat, int s, int c) {
    if constexpr (IN_BF) {
        us4 v = *reinterpret_cast<const us4*>(
            (const unsigned short*)feat + (size_t)s * D + c);
        return make_float4(bf2f(v[0]), bf2f(v[1]), bf2f(v[2]), bf2f(v[3]));
    } else {
        return *reinterpret_cast<const float4*>((const float*)feat + (size_t)s * D + c);
    }
}

template <int IN_BF, int OUT_BF, int BR, int WSEP>
__global__ void __launch_bounds__(256) gather_seg_kernel(
    const void* __restrict__ feat, const float* __restrict__ w_num,
    const float* __restrict__ w_den, const int* __restrict__ sorted_src,
    const float* __restrict__ sorted_w,
    const int* __restrict__ off, const int* __restrict__ bsum,
    const int* __restrict__ cnt, int binBase, int sortBase,
    const float* __restrict__ bias,
    void* __restrict__ out, int n_dst)
{
    int row = blockIdx.x * 8 + (threadIdx.x >> 5);
    if (row >= n_dst) return;
    int c = (threadIdx.x & 31) << 2;
    int bin = binBase + row;
    int start = off[bin] + sortBase;
    if (bsum) start += bsum[bin >> 12];
    const int* sp = sorted_src + start;
    const float* wp = WSEP ? (sorted_w + start) : nullptr;
    int n = cnt[bin];
    float inv = 1.0f / w_den[row];
    float a0 = 0.f, a1 = 0.f, a2 = 0.f, a3 = 0.f;
    int i = 0;
    for (; i + 4 <= n; i += 4) {
        int s0 = sp[i], s1 = sp[i + 1], s2 = sp[i + 2], s3 = sp[i + 3];
        float w0, w1, w2, w3;
        if constexpr (WSEP) {
            w0 = wp[i]; w1 = wp[i + 1]; w2 = wp[i + 2]; w3 = wp[i + 3];
        } else {
            w0 = w_num[s0]; w1 = w_num[s1]; w2 = w_num[s2]; w3 = w_num[s3];
        }
        float4 f0 = ldrow4<IN_BF>(feat, s0, c);
        float4 f1 = ldrow4<IN_BF>(feat, s1, c);
        float4 f2 = ldrow4<IN_BF>(feat, s2, c);
        float4 f3 = ldrow4<IN_BF>(feat, s3, c);
        a0 = fmaf(w0, f0.x, a0); a1 = fmaf(w0, f0.y, a1);
        a2 = fmaf(w0, f0.z, a2); a3 = fmaf(w0, f0.w, a3);
        a0 = fmaf(w1, f1.x, a0); a1 = fmaf(w1, f1.y, a1);
        a2 = fmaf(w1, f1.z, a2); a3 = fmaf(w1, f1.w, a3);
        a0 = fmaf(w2, f2.x, a0); a1 = fmaf(w2, f2.y, a1);
        a2 = fmaf(w2, f2.z, a2); a3 = fmaf(w2, f2.w, a3);
        a0 = fmaf(w3, f3.x, a0); a1 = fmaf(w3, f3.y, a1);
        a2 = fmaf(w3, f3.z, a2); a3 = fmaf(w3, f3.w, a3);
    }
    for (; i < n; ++i) {
        int s0 = sp[i];
        float w0 = WSEP ? wp[i] : w_num[s0];
        float4 f0 = ldrow4<IN_BF>(feat, s0, c);
        a0 = fmaf(w0, f0.x, a0); a1 = fmaf(w0, f0.y, a1);
        a2 = fmaf(w0, f0.z, a2); a3 = fmaf(w0, f0.w, a3);
    }
    a0 *= inv; a1 *= inv; a2 *= inv; a3 *= inv;
    if constexpr (BR) {
        float4 bv = *reinterpret_cast<const float4*>(bias + c);
        a0 = fmaxf(a0 + bv.x, 0.f); a1 = fmaxf(a1 + bv.y, 0.f);
        a2 = fmaxf(a2 + bv.z, 0.f); a3 = fmaxf(a3 + bv.w, 0.f);
    }
    if constexpr (OUT_BF) {
        us4 o = { f2bf(a0), f2bf(a1), f2bf(a2), f2bf(a3) };
        *reinterpret_cast<us4*>((unsigned short*)out + (size_t)row * D + c) = o;
    } else {
        float4 o = make_float4(a0, a1, a2, a3);
        *reinterpret_cast<float4*>((float*)out + (size_t)row * D + c) = o;
    }
}

// ---------------------------------------------------------------------------
// Tier-A gather: 16 lanes/row, 16 rows/block, BRANCHLESS padded 4-way loop.
// Items past the segment end use weight 0 + index clamped to [0, n_src)
// (over-reads stay inside d_ws; clamped feat rows are finite) -> the latency
// chain is ceil(n/4) iterations with no serial scalar tail.
// ---------------------------------------------------------------------------
template <int OUT_BF, int BR>
__global__ void __launch_bounds__(256) gather16_kernel(
    const unsigned short* __restrict__ feat,   // [n_src, D] bf16
    const float* __restrict__ w_den,           // [n_dst]
    const int*   __restrict__ sorted_src,      // [I] grouped by dst
    const float* __restrict__ sorted_w,        // [I] pre-gathered weights
    const int*   __restrict__ off,             // [n_dst] absolute starts
    const int*   __restrict__ cnt,             // [n_dst] lengths
    const float* __restrict__ bias,
    void* __restrict__ out, int n_dst, int n_src)
{
    int row = blockIdx.x * 16 + (threadIdx.x >> 4);
    if (row >= n_dst) return;
    int c = (threadIdx.x & 15) << 3;    // 8 elems per lane
    int start = off[row];
    const int* sp = sorted_src + start;
    const float* wp = sorted_w + start;
    int n = cnt[row];
    const int smax = n_src - 1;
    float inv = 1.0f / w_den[row];
    float a[8];
    #pragma unroll
    for (int j = 0; j < 8; ++j) a[j] = 0.f;
    for (int i = 0; i < n; i += 4) {
        int s0 = min(sp[i], smax);
        int s1 = min(sp[i + 1], smax);
        int s2 = min(sp[i + 2], smax);
        int s3 = min(sp[i + 3], smax);
        float w0 = wp[i];
        float w1 = (i + 1 < n) ? wp[i + 1] : 0.f;
        float w2 = (i + 2 < n) ? wp[i + 2] : 0.f;
        float w3 = (i + 3 < n) ? wp[i + 3] : 0.f;
        us8 f0 = *reinterpret_cast<const us8*>(feat + (size_t)s0 * D + c);
        us8 f1 = *reinterpret_cast<const us8*>(feat + (size_t)s1 * D + c);
        us8 f2 = *reinterpret_cast<const us8*>(feat + (size_t)s2 * D + c);
        us8 f3 = *reinterpret_cast<const us8*>(feat + (size_t)s3 * D + c);
        #pragma unroll
        for (int j = 0; j < 8; ++j) a[j] = fmaf(w0, bf2f(f0[j]), a[j]);
        #pragma unroll
        for (int j = 0; j < 8; ++j) a[j] = fmaf(w1, bf2f(f1[j]), a[j]);
        #pragma unroll
        for (int j = 0; j < 8; ++j) a[j] = fmaf(w2, bf2f(f2[j]), a[j]);
        #pragma unroll
        for (int j = 0; j < 8; ++j) a[j] = fmaf(w3, bf2f(f3[j]), a[j]);
    }
    #pragma unroll
    for (int j = 0; j < 8; ++j) a[j] *= inv;
    if constexpr (BR) {
        float4 bv0 = *reinterpret_cast<const float4*>(bias + c);
        float4 bv1 = *reinterpret_cast<const float4*>(bias + c + 4);
        a[0] = fmaxf(a[0] + bv0.x, 0.f); a[1] = fmaxf(a[1] + bv0.y, 0.f);
        a[2] = fmaxf(a[2] + bv0.z, 0.f); a[3] = fmaxf(a[3] + bv0.w, 0.f);
        a[4] = fmaxf(a[4] + bv1.x, 0.f); a[5] = fmaxf(a[5] + bv1.y, 0.f);
        a[6] = fmaxf(a[6] + bv1.z, 0.f); a[7] = fmaxf(a[7] + bv1.w, 0.f);
    }
    if constexpr (OUT_BF) {
        us8 o = { f2bf(a[0]), f2bf(a[1]), f2bf(a[2]), f2bf(a[3]),
                  f2bf(a[4]), f2bf(a[5]), f2bf(a[6]), f2bf(a[7]) };
        *reinterpret_cast<us8*>((unsigned short*)out + (size_t)row * D + c) = o;
    } else {
        float* op = (float*)out + (size_t)row * D + c;
        *reinterpret_cast<float4*>(op)     = make_float4(a[0], a[1], a[2], a[3]);
        *reinterpret_cast<float4*>(op + 4) = make_float4(a[4], a[5], a[6], a[7]);
    }
}

// ---------------------------------------------------------------------------
// LDS staging helpers for MFMA GEMMs. NT = thread count.
// ---------------------------------------------------------------------------
template <int NT, int ROWS>
__device__ __forceinline__ void stage_A(
    unsigned short* A_lds, const float* __restrict__ in, int r0, int nrows, int tid)
{
    #pragma unroll
    for (int it = 0; it < ROWS * 32 / NT; ++it) {
        int e   = tid + it * NT;
        int row = e >> 5;
        int c4  = (e & 31) << 2;
        int grow = r0 + row;
        float4 v = make_float4(0.f, 0.f, 0.f, 0.f);
        if (grow < nrows)
            v = *reinterpret_cast<const float4*>(in + (size_t)grow * D + c4);
        us4 b = { f2bf(v.x), f2bf(v.y), f2bf(v.z), f2bf(v.w) };
        *reinterpret_cast<us4*>(A_lds + row * LDSP + c4) = b;
    }
}

template <int NT, int ROWS>
__device__ __forceinline__ void stage_A_bf(
    unsigned short* A_lds, const unsigned short* __restrict__ in,
    int r0, int nrows, int tid)
{
    #pragma unroll
    for (int it = 0; it < ROWS * 16 / NT; ++it) {
        int e   = tid + it * NT;
        int row = e >> 4;
        int c8  = (e & 15) << 3;
        int grow = r0 + row;
        bf16x8 v;
        #pragma unroll
        for (int j = 0; j < 8; ++j) v[j] = 0;
        if (grow < nrows)
            v = *reinterpret_cast<const bf16x8*>(in + (size_t)grow * D + c8);
        *reinterpret_cast<bf16x8*>(A_lds + row * LDSP + c8) = v;
    }
}

template <int NT>
__device__ __forceinline__ void stage_Wt(
    unsigned short* W_lds, const float* __restrict__ W, int tid)
{
    #pragma unroll
    for (int it = 0; it < D * 32 / NT; ++it) {
        int e   = tid + it * NT;
        int row = e >> 5;
        int c4  = (e & 31) << 2;
        float4 v = *reinterpret_cast<const float4*>(W + (size_t)row * D + c4);
        us4 b = { f2bf(v.x), f2bf(v.y), f2bf(v.z), f2bf(v.w) };
        *reinterpret_cast<us4*>(W_lds + row * LDSP + c4) = b;
    }
}

__device__ __forceinline__ void mfma_16x128(
    const unsigned short* A_lds, const unsigned short* W_lds,
    int wv, int lane, f32x4 acc[8])
{
    const int lr = lane & 15;
    const int lk = (lane >> 4) << 3;
    const unsigned short* arow = A_lds + (wv * 16 + lr) * LDSP;
    #pragma unroll
    for (int kt = 0; kt < 4; ++kt) {
        bf16x8 af = *reinterpret_cast<const bf16x8*>(arow + kt * 32 + lk);
        #pragma unroll
        for (int ct = 0; ct < 8; ++ct) {
            bf16x8 bfr = *reinterpret_cast<const bf16x8*>(
                W_lds + (ct * 16 + lr) * LDSP + kt * 32 + lk);
            acc[ct] = __builtin_amdgcn_mfma_f32_16x16x32_bf16(af, bfr, acc[ct], 0, 0, 0);
        }
    }
}

template <int MODE>
__global__ void __launch_bounds__(256) mfma_gemm_kernel(
    const float* __restrict__ in, const float* __restrict__ W,
    const float* __restrict__ bias, float* __restrict__ out, int nrows)
{
    __shared__ unsigned short A_lds[64 * LDSP];
    __shared__ unsigned short W_lds[D * LDSP];

    const int tid  = threadIdx.x;
    const int r0   = blockIdx.x * 64;
    const int wv   = tid >> 6;
    const int lane = tid & 63;

    stage_A<256, 64>(A_lds, in, r0, nrows, tid);
    stage_Wt<256>(W_lds, W, tid);
    __syncthreads();

    f32x4 acc[8];
    #pragma unroll
    for (int ct = 0; ct < 8; ++ct) acc[ct] = (f32x4){0.f, 0.f, 0.f, 0.f};
    mfma_16x128(A_lds, W_lds, wv, lane, acc);

    const int lr = lane & 15;
    const int rb = r0 + wv * 16 + ((lane >> 4) << 2);
    #pragma unroll
    for (int ct = 0; ct < 8; ++ct) {
        int col = ct * 16 + lr;
        float bv = bias[col];
        #pragma unroll
        for (int i = 0; i < 4; ++i) {
            int row = rb + i;
            if (row >= nrows) continue;
            float x = acc[ct][i] + bv;
            if (MODE == 2) x = fmaxf(x, 0.f);
            out[(size_t)row * D + col] = x;
        }
    }
}

template <int RBF>
__global__ void __launch_bounds__(256) mfma_dualgemm_kernel(
    const float* __restrict__ inL, const float* __restrict__ WL,
    const float* __restrict__ bL,
    const void*  __restrict__ inR, const float* __restrict__ WR,
    const float* __restrict__ bR,
    float* __restrict__ out, int nrows)
{
    __shared__ unsigned short A_lds[64 * LDSP];
    __shared__ unsigned short W_lds[D * LDSP];

    const int tid  = threadIdx.x;
    const int r0   = blockIdx.x * 64;
    const int wv   = tid >> 6;
    const int lane = tid & 63;

    f32x4 acc0[8], acc1[8];
    #pragma unroll
    for (int ct = 0; ct < 8; ++ct) {
        acc0[ct] = (f32x4){0.f, 0.f, 0.f, 0.f};
        acc1[ct] = (f32x4){0.f, 0.f, 0.f, 0.f};
    }

    stage_A<256, 64>(A_lds, inL, r0, nrows, tid);
    stage_Wt<256>(W_lds, WL, tid);
    __syncthreads();
    mfma_16x128(A_lds, W_lds, wv, lane, acc0);
    __syncthreads();

    if constexpr (RBF)
        stage_A_bf<256, 64>(A_lds, (const unsigned short*)inR, r0, nrows, tid);
    else
        stage_A<256, 64>(A_lds, (const float*)inR, r0, nrows, tid);
    stage_Wt<256>(W_lds, WR, tid);
    __syncthreads();
    mfma_16x128(A_lds, W_lds, wv, lane, acc1);

    const int lr = lane & 15;
    const int rb = r0 + wv * 16 + ((lane >> 4) << 2);
    #pragma unroll
    for (int ct = 0; ct < 8; ++ct) {
        int col = ct * 16 + lr;
        float bvL = bL[col];
        float bvR = bR[col];
        #pragma unroll
        for (int i = 0; i < 4; ++i) {
            int row = rb + i;
            if (row >= nrows) continue;
            float x = (acc0[ct][i] + bvL) + fmaxf(acc1[ct][i] + bvR, 0.f);
            out[(size_t)row * D + col] = x;
        }
    }
}

// ---------------------------------------------------------------------------
// TRIPLE GEMM (tier A), 512 threads / 128-row tile (round-10 form):
//   eout = (inL @ WL^T + bL) + relu(inR_bf @ WR^T + bR)   -> outE (f32)
//   Z    = eout @ WZ^T                                     -> outZ (bf16)
// ---------------------------------------------------------------------------
#define TROWS 128
__global__ void __launch_bounds__(512) mfma_trigemm_kernel(
    const float* __restrict__ inL, const float* __restrict__ WL,
    const float* __restrict__ bL,
    const unsigned short* __restrict__ inR, const float* __restrict__ WR,
    const float* __restrict__ bR,
    const float* __restrict__ WZ,
    float* __restrict__ outE, unsigned short* __restrict__ outZ, int nrows)
{
    __shared__ unsigned short A_lds[TROWS * LDSP];
    __shared__ unsigned short W_lds[D * LDSP];

    const int tid  = threadIdx.x;
    const int r0   = blockIdx.x * TROWS;
    const int wv   = tid >> 6;          // 0..7
    const int lane = tid & 63;
    const int lr   = lane & 15;
    const int lg   = lane >> 4;
    const int rb   = r0 + wv * 16 + (lg << 2);

    f32x4 acc0[8], acc1[8];
    #pragma unroll
    for (int ct = 0; ct < 8; ++ct) {
        acc0[ct] = (f32x4){0.f, 0.f, 0.f, 0.f};
        acc1[ct] = (f32x4){0.f, 0.f, 0.f, 0.f};
    }

    // pass 0: L = efeat (f32) x W_ef
    stage_A<512, TROWS>(A_lds, inL, r0, nrows, tid);
    stage_Wt<512>(W_lds, WL, tid);
    __syncthreads();
    mfma_16x128(A_lds, W_lds, wv, lane, acc0);
    __syncthreads();

    // pass 1: R = acc_e (bf16) x W_ve
    stage_A_bf<512, TROWS>(A_lds, inR, r0, nrows, tid);
    stage_Wt<512>(W_lds, WR, tid);
    __syncthreads();
    mfma_16x128(A_lds, W_lds, wv, lane, acc1);

    // epilogue 1: acc0 <- eout = (acc0+bL) + relu(acc1+bR); store f32
    #pragma unroll
    for (int ct = 0; ct < 8; ++ct) {
        int col = ct * 16 + lr;
        float bvL = bL[col];
        float bvR = bR[col];
        #pragma unroll
        for (int i = 0; i < 4; ++i) {
            float x = (acc0[ct][i] + bvL) + fmaxf(acc1[ct][i] + bvR, 0.f);
            acc0[ct][i] = x;
            int row = rb + i;
            if (row < nrows) outE[(size_t)row * D + col] = x;
        }
    }

    __syncthreads();   // all pass-1 LDS reads done before restage

    // restage eout tile (bf16): each wave fills its own 16-row slab
    #pragma unroll
    for (int ct = 0; ct < 8; ++ct) {
        int col = ct * 16 + lr;
        #pragma unroll
        for (int i = 0; i < 4; ++i) {
            A_lds[(wv * 16 + (lg << 2) + i) * LDSP + col] = f2bf(acc0[ct][i]);
        }
    }
    stage_Wt<512>(W_lds, WZ, tid);
    __syncthreads();

    // pass 2: Z = eout x W_ev  (acc1 reused)
    #pragma unroll
    for (int ct = 0; ct < 8; ++ct) acc1[ct] = (f32x4){0.f, 0.f, 0.f, 0.f};
    mfma_16x128(A_lds, W_lds, wv, lane, acc1);

    #pragma unroll
    for (int ct = 0; ct < 8; ++ct) {
        int col = ct * 16 + lr;
        #pragma unroll
        for (int i = 0; i < 4; ++i) {
            int row = rb + i;
            if (row < nrows) outZ[(size_t)row * D + col] = f2bf(acc1[ct][i]);
        }
    }
}

// ---------------------------------------------------------------------------
extern "C" void kernel_launch(void* const* d_in, const int* in_sizes, int n_in,
                              void* d_out, int out_size, void* d_ws, size_t ws_size,
                              hipStream_t stream)
{
    const float* vfeat = (const float*)d_in[0];
    const float* efeat = (const float*)d_in[1];
    const float* vrw   = (const float*)d_in[2];
    const float* vrs   = (const float*)d_in[3];
    const float* erw   = (const float*)d_in[4];
    const float* ers   = (const float*)d_in[5];
    const float* W_ve  = (const float*)d_in[6];
    const float* b_ve  = (const float*)d_in[7];
    const float* W_ev  = (const float*)d_in[8];
    const float* b_ev  = (const float*)d_in[9];
    const float* W_ef  = (const float*)d_in[10];
    const float* b_ef  = (const float*)d_in[11];
    const int* node_idx = (const int*)d_in[12];
    const int* edge_idx = (const int*)d_in[13];

    const int V = in_sizes[0] / D;   // 100000
    const int E = in_sizes[1] / D;   // 40000
    const int I = in_sizes[12];      // 600000
    const int EV = E + V;

    float* vfeat_out = (float*)d_out;                  // [V, D]
    float* efeat_out = (float*)d_out + (size_t)V * D;  // [E, D]

    const int NBE = (E + 63) >> 6;    // 625 edge buckets (64 bins each)
    const int NBV = (V + 127) >> 7;   // 782 node buckets (128 bins each)
    const int HB  = (I + PART_ELEMS - 1) / PART_ELEMS;  // 147

    // ---- tier-A workspace layout (no gCnt; atomic-free build) ----
    int* bktBaseE   = (int*)d_ws;                 // [NBE+1]
    int* bktBaseV   = bktBaseE + NBE + 1;         // [NBV+1]
    int* blockBaseE = bktBaseV + NBV + 1;         // [HB*NBE]
    int* blockBaseV = blockBaseE + (size_t)HB * NBE; // [HB*NBV]
    int* offE       = blockBaseV + (size_t)HB * NBV; // [E]
    int* cntE       = offE + E;                   // [E]
    int* offV       = cntE + E;                   // [V]
    int* cntV       = offV + V;                   // [V]
    int* sorted_n   = cntV + V;                   // [I]
    int* sorted_e   = sorted_n + I;               // [I]
    float* sorted_wn = (float*)(sorted_e + I);    // [I] pre-gathered vrw
    float* sorted_we = sorted_wn + I;             // [I] pre-gathered erw
    size_t fixed_ints = (size_t)((int*)(sorted_we + I) - (int*)d_ws);
    fixed_ints = (fixed_ints + 3) & ~(size_t)3;   // 16B-align the union region
    // union region: pairsE/pairsV (2I ints, dead after bin_csr)  vs  z_bf
    int* pairsE = (int*)d_ws + fixed_ints;
    int* pairsV = pairsE + I;
    unsigned short* z_bf = (unsigned short*)pairsE;   // [E*D] born at trigemm
    size_t union_bytes = (size_t)2 * I * 4;
    if ((size_t)E * D * 2 > union_bytes) union_bytes = (size_t)E * D * 2;
    size_t ws_needA = fixed_ints * 4 + union_bytes + 64;  // +64: gather over-read pad

    // old tier-B layout (f32 gathers, bsum-folded)
    size_t ws_needB = ((size_t)2 * EV + 64 + (size_t)4 * I) * sizeof(int);

    if (ws_size >= ws_needA && NBE <= 1024 && NBV <= 1024) {
        // ======== tier A: bucketed CSR + bf16 gathers + fused triple GEMM ====
        unsigned short* vfeat_bf = (unsigned short*)d_out;       // [V*D]
        unsigned short* acc_e_bf = vfeat_bf + (size_t)V * D;     // [E*D]
        // 25.6 + 10.2 MB <= 51.2 MB f32 region; dead before gather2 writes.

        part_hist_kernel<<<HB, 1024, 0, stream>>>(
            node_idx, edge_idx, blockBaseE, blockBaseV, NBE, NBV, I);
        cvt_f32_bf16_kernel<<<2048, 256, 0, stream>>>(vfeat, vfeat_bf, V * D / 4);
        bucket_scan_kernel<<<2, 1024, 0, stream>>>(
            blockBaseE, bktBaseE, NBE, blockBaseV, bktBaseV, NBV, HB);
        part_scatter_kernel<<<HB, 1024, 0, stream>>>(
            node_idx, edge_idx, bktBaseE, bktBaseV, blockBaseE, blockBaseV,
            pairsE, pairsV, NBE, NBV, I);
        bin_csr_kernel<<<NBE + NBV, 256, 0, stream>>>(
            pairsE, pairsV, bktBaseE, bktBaseV,
            offE, cntE, offV, cntV, sorted_n, sorted_e,
            vrw, erw, sorted_wn, sorted_we, NBE, NBV, E, V);

        // g1: nodes -> hyperedges (bf16 table, bf16 out, padded 16 lanes/row)
        gather16_kernel<1, 0><<<(E + 15) / 16, 256, 0, stream>>>(
            vfeat_bf, ers, sorted_n, sorted_wn, offE, cntE, nullptr,
            acc_e_bf, E, V);

        // eout = (efeat@W_ef^T+b_ef) + relu(acc_e@W_ve^T+b_ve);  Z = eout@W_ev^T
        mfma_trigemm_kernel<<<(E + TROWS - 1) / TROWS, 512, 0, stream>>>(
            efeat, W_ef, b_ef, acc_e_bf, W_ve, b_ve, W_ev, efeat_out, z_bf, E);

        // g2: vfeat_out = relu( (sum w * Z[e]) / vrs + b_ev )
        gather16_kernel<0, 1><<<(V + 15) / 16, 256, 0, stream>>>(
            z_bf, vrs, sorted_e, sorted_we, offV, cntV, b_ev,
            vfeat_out, V, E);
    } else if (ws_size >= ws_needB) {
        // ======== tier B: old atomic hist + place, f32 gathers ========
        int* cnt_cat  = (int*)d_ws;
        int* off_cat  = cnt_cat + EV;
        int* bsum     = off_cat + EV;
        int* rank_e   = bsum + 64;
        int* rank_v   = rank_e + I;
        int* sorted_nb = rank_v + I;
        int* sorted_eb = sorted_nb + I;
        const int inc_blocks  = (I + 255) / 256;
        const int half_blocks = (((I + 1) >> 1) + 255) / 256;
        const int nb = (EV + SCAN_CHUNK - 1) / SCAN_CHUNK;
        float* acc_e = vfeat_out;

        hipMemsetAsync(cnt_cat, 0, (size_t)EV * sizeof(int), stream);
        hist_rank_kernel<<<half_blocks, 256, 0, stream>>>(
            node_idx, edge_idx, cnt_cat, rank_e, rank_v, E, I);
        scan_block_kernel<<<nb, 1024, 0, stream>>>(cnt_cat, off_cat, bsum, EV);
        scan_block_kernel<<<1, 1024, 0, stream>>>(bsum, bsum, nullptr, nb);
        place_kernel<<<inc_blocks, 256, 0, stream>>>(
            node_idx, edge_idx, rank_e, rank_v, off_cat, bsum, sorted_nb, sorted_eb, E, I);
        gather_seg_kernel<0, 0, 0, 0><<<(E + 7) / 8, 256, 0, stream>>>(
            vfeat, vrw, ers, sorted_nb, nullptr, off_cat, bsum, cnt_cat, 0, 0,
            nullptr, acc_e, E);
        mfma_dualgemm_kernel<0><<<(E + 63) / 64, 256, 0, stream>>>(
            efeat, W_ef, b_ef, acc_e, W_ve, b_ve, efeat_out, E);
        gather_seg_kernel<0, 0, 0, 0><<<(V + 7) / 8, 256, 0, stream>>>(
            efeat_out, erw, vrs, sorted_eb, nullptr, off_cat, bsum, cnt_cat, E, -I,
            nullptr, vfeat_out, V);
        mfma_gemm_kernel<2><<<(V + 63) / 64, 256, 0, stream>>>(
            vfeat_out, W_ev, b_ev, vfeat_out, V);
    } else {
        // ======== tier C: atomic fallback ========
        float* acc_e = vfeat_out;
        const int sb = (I * 32 + 255) / 256;
        hipMemsetAsync(acc_e, 0, (size_t)E * D * sizeof(float), stream);
        scatter_kernel<<<sb, 256, 0, stream>>>(vfeat, vrw, ers, node_idx, edge_idx, acc_e, I);
        mfma_dualgemm_kernel<0><<<(E + 63) / 64, 256, 0, stream>>>(
            efeat, W_ef, b_ef, acc_e, W_ve, b_ve, efeat_out, E);
        hipMemsetAsync(vfeat_out, 0, (size_t)V * D * sizeof(float), stream);
        scatter_kernel<<<sb, 256, 0, stream>>>(efeat_out, erw, vrs, edge_idx, node_idx, vfeat_out, I);
        mfma_gemm_kernel<2><<<(V + 63) / 64, 256, 0, stream>>>(vfeat_out, W_ev, b_ev, vfeat_out, V);
    }
}

// Round 15
// 143.297 us; speedup vs baseline: 1.0257x; 1.0257x over previous
//
#include <hip/hip_runtime.h>

#define D 128
#define SCAN_CHUNK 4096    // elements per scan block (old tier-B path)
#define PART_ELEMS 4096    // incidences per partition block (1024 thr x 4)
#define MAXB 2048          // max buckets per direction (LDS arrays)

typedef __attribute__((ext_vector_type(8))) short   bf16x8;
typedef __attribute__((ext_vector_type(4))) float   f32x4;
typedef __attribute__((ext_vector_type(4))) unsigned short us4;
typedef __attribute__((ext_vector_type(8))) unsigned short us8;

#define LDSP (D + 8)       // bf16 LDS row pitch: 136 elems = 272 B (2-way max)

__device__ __forceinline__ unsigned short f2bf(float x) {
    union { float f; unsigned u; } v; v.f = x;
    unsigned r = v.u + 0x7fffu + ((v.u >> 16) & 1u);   // round-to-nearest-even
    return (unsigned short)(r >> 16);
}
__device__ __forceinline__ float bf2f(unsigned short u) {
    union { unsigned u; float f; } v; v.u = ((unsigned)u) << 16; return v.f;
}

// ---------------------------------------------------------------------------
// f32 -> bf16 bulk convert (tier B/C helper; tier A folds it into the scan)
// ---------------------------------------------------------------------------
__global__ void __launch_bounds__(256) cvt_f32_bf16_kernel(
    const float* __restrict__ in, unsigned short* __restrict__ out, int n4)
{
    int stride = gridDim.x * 256;
    for (int i = blockIdx.x * 256 + threadIdx.x; i < n4; i += stride) {
        float4 v = *reinterpret_cast<const float4*>(in + (size_t)i * 4);
        us4 b = { f2bf(v.x), f2bf(v.y), f2bf(v.z), f2bf(v.w) };
        *reinterpret_cast<us4*>(out + (size_t)i * 4) = b;
    }
}

// ===========================================================================
// Bucketed CSR builder (tier A) — atomic-free, memset-free variant.
// ===========================================================================

__global__ void __launch_bounds__(1024) part_hist_kernel(
    const int* __restrict__ node_idx, const int* __restrict__ edge_idx,
    int* __restrict__ blockBaseE, int* __restrict__ blockBaseV,
    int NBE, int NBV, int I)
{
    __shared__ int hE[MAXB];
    __shared__ int hV[MAXB];
    const int tid = threadIdx.x, blk = blockIdx.x;
    for (int k = tid; k < NBE; k += 1024) hE[k] = 0;
    for (int k = tid; k < NBV; k += 1024) hV[k] = 0;
    __syncthreads();
    const int base = blk * PART_ELEMS;
    #pragma unroll
    for (int j = 0; j < PART_ELEMS / 1024; ++j) {
        int i = base + j * 1024 + tid;
        if (i < I) {
            atomicAdd(&hE[edge_idx[i] >> 6], 1);
            atomicAdd(&hV[node_idx[i] >> 7], 1);
        }
    }
    __syncthreads();
    for (int k = tid; k < NBE; k += 1024)
        blockBaseE[(size_t)blk * NBE + k] = hE[k];
    for (int k = tid; k < NBV; k += 1024)
        blockBaseV[(size_t)blk * NBV + k] = hV[k];
}

// FAT dispatch: blocks 0/1 do the bucket scans (edge dir / node dir);
// blocks >= 2 run the vfeat f32->bf16 convert on the otherwise-idle CUs.
// (BW+LDS fusion — no returning global atomics, unlike r6's failed fusion.)
__global__ void __launch_bounds__(1024) fat_scan_cvt_kernel(
    int* __restrict__ blockBaseE, int* __restrict__ bktBaseE, int nE,
    int* __restrict__ blockBaseV, int* __restrict__ bktBaseV, int nV,
    int HB,
    const float* __restrict__ vf, unsigned short* __restrict__ vf_bf, int n4)
{
    if ((int)blockIdx.x >= 2) {
        // ---- convert blocks ----
        int b = blockIdx.x - 2;
        int stride = (gridDim.x - 2) * 1024;
        for (int i = b * 1024 + threadIdx.x; i < n4; i += stride) {
            float4 v = *reinterpret_cast<const float4*>(vf + (size_t)i * 4);
            us4 o = { f2bf(v.x), f2bf(v.y), f2bf(v.z), f2bf(v.w) };
            *reinterpret_cast<us4*>(vf_bf + (size_t)i * 4) = o;
        }
        return;
    }
    // ---- scan blocks ----
    __shared__ int lds[1024];
    int* blockBase = blockIdx.x ? blockBaseV : blockBaseE;
    int* bktBase   = blockIdx.x ? bktBaseV : bktBaseE;
    const int n    = blockIdx.x ? nV : nE;
    const int tid  = threadIdx.x;
    int total = 0;
    if (tid < n) {
        size_t idx = tid;
        int blk = 0;
        for (; blk + 4 <= HB; blk += 4) {
            int t0 = blockBase[idx];
            int t1 = blockBase[idx + (size_t)n];
            int t2 = blockBase[idx + (size_t)2 * n];
            int t3 = blockBase[idx + (size_t)3 * n];
            blockBase[idx] = total;
            blockBase[idx + (size_t)n] = total + t0;
            blockBase[idx + (size_t)2 * n] = total + t0 + t1;
            blockBase[idx + (size_t)3 * n] = total + t0 + t1 + t2;
            total += t0 + t1 + t2 + t3;
            idx += (size_t)4 * n;
        }
        for (; blk < HB; ++blk) {
            int t = blockBase[idx];
            blockBase[idx] = total;
            total += t;
            idx += n;
        }
    }
    lds[tid] = (tid < n) ? total : 0;
    __syncthreads();
    for (int o = 1; o < 1024; o <<= 1) {
        int t = lds[tid];
        int u = (tid >= o) ? lds[tid - o] : 0;
        __syncthreads();
        lds[tid] = t + u;
        __syncthreads();
    }
    if (tid < n) bktBase[tid] = lds[tid] - total;   // exclusive
    if (tid == 0) bktBase[n] = lds[1023];           // total
}

__global__ void __launch_bounds__(1024) part_scatter_kernel(
    const int* __restrict__ node_idx, const int* __restrict__ edge_idx,
    const int* __restrict__ bktBaseE, const int* __restrict__ bktBaseV,
    const int* __restrict__ blockBaseE, const int* __restrict__ blockBaseV,
    int* __restrict__ pairsE, int* __restrict__ pairsV,
    int NBE, int NBV, int I)
{
    __shared__ int bE[MAXB];
    __shared__ int bV[MAXB];
    const int tid = threadIdx.x, blk = blockIdx.x;
    for (int k = tid; k < NBE; k += 1024)
        bE[k] = bktBaseE[k] + blockBaseE[(size_t)blk * NBE + k];
    for (int k = tid; k < NBV; k += 1024)
        bV[k] = bktBaseV[k] + blockBaseV[(size_t)blk * NBV + k];
    __syncthreads();
    const int base = blk * PART_ELEMS;
    #pragma unroll
    for (int j = 0; j < PART_ELEMS / 1024; ++j) {
        int i = base + j * 1024 + tid;
        if (i < I) {
            int ev = edge_idx[i], nv = node_idx[i];
            int pE = atomicAdd(&bE[ev >> 6], 1);
            pairsE[pE] = (nv << 6) | (ev & 63);
            int pV = atomicAdd(&bV[nv >> 7], 1);
            pairsV[pV] = (ev << 7) | (nv & 127);
        }
    }
}

// K4: per-bucket bin histogram -> scan -> sorted payloads + pre-gathered weights
__global__ void __launch_bounds__(256) bin_csr_kernel(
    const int* __restrict__ pairsE, const int* __restrict__ pairsV,
    const int* __restrict__ bktBaseE, const int* __restrict__ bktBaseV,
    int* __restrict__ offE, int* __restrict__ cntE,
    int* __restrict__ offV, int* __restrict__ cntV,
    int* __restrict__ sorted_n, int* __restrict__ sorted_e,
    const float* __restrict__ vrw, const float* __restrict__ erw,
    float* __restrict__ sorted_wn, float* __restrict__ sorted_we,
    int NBE, int NBV, int E, int V)
{
    __shared__ int cnt[128], off[128], cur[128];
    const int tid = threadIdx.x;
    const int blk = blockIdx.x;
    if (blk < NBE) {
        const int k = blk, lo = bktBaseE[k], hi = bktBaseE[k + 1];
        if (tid < 64) cnt[tid] = 0;
        __syncthreads();
        for (int i = lo + tid; i < hi; i += 256)
            atomicAdd(&cnt[pairsE[i] & 63], 1);
        __syncthreads();
        if (tid < 64) off[tid] = cnt[tid];
        __syncthreads();
        for (int o = 1; o < 64; o <<= 1) {
            int t = 0;
            if (tid < 64) { t = off[tid]; if (tid >= o) t += off[tid - o]; }
            __syncthreads();
            if (tid < 64) off[tid] = t;
            __syncthreads();
        }
        if (tid < 64) {
            int excl = off[tid] - cnt[tid];
            int bin = k * 64 + tid;
            if (bin < E) { cntE[bin] = cnt[tid]; offE[bin] = lo + excl; }
            cur[tid] = 0;
            off[tid] = excl;
        }
        __syncthreads();
        for (int i = lo + tid; i < hi; i += 256) {
            int w = pairsE[i];
            int b = w & 63;
            int r = atomicAdd(&cur[b], 1);
            int src = w >> 6;
            int pos = lo + off[b] + r;
            sorted_n[pos] = src;
            sorted_wn[pos] = vrw[src];
        }
    } else {
        const int k = blk - NBE, lo = bktBaseV[k], hi = bktBaseV[k + 1];
        if (tid < 128) cnt[tid] = 0;
        __syncthreads();
        for (int i = lo + tid; i < hi; i += 256)
            atomicAdd(&cnt[pairsV[i] & 127], 1);
        __syncthreads();
        if (tid < 128) off[tid] = cnt[tid];
        __syncthreads();
        for (int o = 1; o < 128; o <<= 1) {
            int t = 0;
            if (tid < 128) { t = off[tid]; if (tid >= o) t += off[tid - o]; }
            __syncthreads();
            if (tid < 128) off[tid] = t;
            __syncthreads();
        }
        if (tid < 128) {
            int excl = off[tid] - cnt[tid];
            int bin = k * 128 + tid;
            if (bin < V) { cntV[bin] = cnt[tid]; offV[bin] = lo + excl; }
            cur[tid] = 0;
            off[tid] = excl;
        }
        __syncthreads();
        for (int i = lo + tid; i < hi; i += 256) {
            int w = pairsV[i];
            int b = w & 127;
            int r = atomicAdd(&cur[b], 1);
            int src = w >> 7;
            int pos = lo + off[b] + r;
            sorted_e[pos] = src;
            sorted_we[pos] = erw[src];
        }
    }
}

// ===========================================================================
// Old CSR builder kernels (tier B fallback) + atomic scatter (tier C)
// ===========================================================================
__global__ void __launch_bounds__(256) scatter_kernel(
    const float* __restrict__ feat, const float* __restrict__ w_num,
    const float* __restrict__ w_den, const int* __restrict__ src_idx,
    const int* __restrict__ dst_idx, float* __restrict__ acc, int n_inc)
{
    int gid = blockIdx.x * 256 + threadIdx.x;
    int inc = gid >> 5;
    if (inc >= n_inc) return;
    int c = (gid & 31) << 2;
    int s = src_idx[inc];
    int t = dst_idx[inc];
    float w = w_num[s] / w_den[t];
    float4 v = *reinterpret_cast<const float4*>(feat + (size_t)s * D + c);
    float* dst = acc + (size_t)t * D + c;
    atomicAdd(dst + 0, w * v.x);
    atomicAdd(dst + 1, w * v.y);
    atomicAdd(dst + 2, w * v.z);
    atomicAdd(dst + 3, w * v.w);
}

__global__ void __launch_bounds__(256) hist_rank_kernel(
    const int* __restrict__ node_idx, const int* __restrict__ edge_idx,
    int* __restrict__ cnt, int* __restrict__ rank_e, int* __restrict__ rank_v,
    int E, int n)
{
    int half = (n + 1) >> 1;
    int i = blockIdx.x * 256 + threadIdx.x;
    if (i >= half) return;
    int nv0 = node_idx[i], ev0 = edge_idx[i];
    int j = i + half;
    if (j < n) {
        int nv1 = node_idx[j], ev1 = edge_idx[j];
        int a = atomicAdd(&cnt[ev0], 1);
        int b = atomicAdd(&cnt[ev1], 1);
        int c = atomicAdd(&cnt[E + nv0], 1);
        int d = atomicAdd(&cnt[E + nv1], 1);
        rank_e[i] = a; rank_e[j] = b;
        rank_v[i] = c; rank_v[j] = d;
    } else {
        rank_e[i] = atomicAdd(&cnt[ev0], 1);
        rank_v[i] = atomicAdd(&cnt[E + nv0], 1);
    }
}

__global__ void __launch_bounds__(1024) scan_block_kernel(
    const int* __restrict__ in, int* __restrict__ out,
    int* __restrict__ blocksums, int n)
{
    __shared__ int lds[1024];
    const int tid = threadIdx.x;
    const int idx = blockIdx.x * SCAN_CHUNK + tid * 4;
    int4 v = make_int4(0, 0, 0, 0);
    if (idx + 3 < n) v = *reinterpret_cast<const int4*>(in + idx);
    else {
        if (idx + 0 < n) v.x = in[idx + 0];
        if (idx + 1 < n) v.y = in[idx + 1];
        if (idx + 2 < n) v.z = in[idx + 2];
        if (idx + 3 < n) v.w = in[idx + 3];
    }
    lds[tid] = v.x + v.y + v.z + v.w;
    __syncthreads();
    for (int off = 1; off < 1024; off <<= 1) {
        int t = lds[tid];
        int u = (tid >= off) ? lds[tid - off] : 0;
        __syncthreads();
        lds[tid] = t + u;
        __syncthreads();
    }
    int excl = tid ? lds[tid - 1] : 0;
    if (blocksums && tid == 1023) blocksums[blockIdx.x] = lds[1023];
    int4 o;
    o.x = excl;
    o.y = o.x + v.x;
    o.z = o.y + v.y;
    o.w = o.z + v.z;
    if (idx + 3 < n) *reinterpret_cast<int4*>(out + idx) = o;
    else {
        if (idx + 0 < n) out[idx + 0] = o.x;
        if (idx + 1 < n) out[idx + 1] = o.y;
        if (idx + 2 < n) out[idx + 2] = o.z;
        if (idx + 3 < n) out[idx + 3] = o.w;
    }
}

__global__ void __launch_bounds__(256) place_kernel(
    const int* __restrict__ node_idx, const int* __restrict__ edge_idx,
    const int* __restrict__ rank_e, const int* __restrict__ rank_v,
    const int* __restrict__ off, const int* __restrict__ bsum,
    int* __restrict__ sorted_n, int* __restrict__ sorted_e,
    int E, int I)
{
    int i = blockIdx.x * 256 + threadIdx.x;
    if (i >= I) return;
    int nv = node_idx[i], ev = edge_idx[i];
    sorted_n[off[ev] + bsum[ev >> 12] + rank_e[i]] = nv;
    int b2 = E + nv;
    sorted_e[off[b2] + bsum[b2 >> 12] - I + rank_v[i]] = ev;
}

// ---------------------------------------------------------------------------
// OLD gather (tier B): 32 lanes/row, f32 table.
// ---------------------------------------------------------------------------
template <int IN_BF>
__device__ __forceinline__ float4 ldrow4(const void* feat, int s, int c) {
    if constexpr (IN_BF) {
        us4 v = *reinterpret_cast<const us4*>(
            (const unsigned short*)feat + (size_t)s * D + c);
        return make_float4(bf2f(v[0]), bf2f(v[1]), bf2f(v[2]), bf2f(v[3]));
    } else {
        return *reinterpret_cast<const float4*>((const float*)feat + (size_t)s * D + c);
    }
}

template <int IN_BF, int OUT_BF, int BR, int WSEP>
__global__ void __launch_bounds__(256) gather_seg_kernel(
    const void* __restrict__ feat, const float* __restrict__ w_num,
    const float* __restrict__ w_den, const int* __restrict__ sorted_src,
    const float* __restrict__ sorted_w,
    const int* __restrict__ off, const int* __restrict__ bsum,
    const int* __restrict__ cnt, int binBase, int sortBase,
    const float* __restrict__ bias,
    void* __restrict__ out, int n_dst)
{
    int row = blockIdx.x * 8 + (threadIdx.x >> 5);
    if (row >= n_dst) return;
    int c = (threadIdx.x & 31) << 2;
    int bin = binBase + row;
    int start = off[bin] + sortBase;
    if (bsum) start += bsum[bin >> 12];
    const int* sp = sorted_src + start;
    const float* wp = WSEP ? (sorted_w + start) : nullptr;
    int n = cnt[bin];
    float inv = 1.0f / w_den[row];
    float a0 = 0.f, a1 = 0.f, a2 = 0.f, a3 = 0.f;
    int i = 0;
    for (; i + 4 <= n; i += 4) {
        int s0 = sp[i], s1 = sp[i + 1], s2 = sp[i + 2], s3 = sp[i + 3];
        float w0, w1, w2, w3;
        if constexpr (WSEP) {
            w0 = wp[i]; w1 = wp[i + 1]; w2 = wp[i + 2]; w3 = wp[i + 3];
        } else {
            w0 = w_num[s0]; w1 = w_num[s1]; w2 = w_num[s2]; w3 = w_num[s3];
        }
        float4 f0 = ldrow4<IN_BF>(feat, s0, c);
        float4 f1 = ldrow4<IN_BF>(feat, s1, c);
        float4 f2 = ldrow4<IN_BF>(feat, s2, c);
        float4 f3 = ldrow4<IN_BF>(feat, s3, c);
        a0 = fmaf(w0, f0.x, a0); a1 = fmaf(w0, f0.y, a1);
        a2 = fmaf(w0, f0.z, a2); a3 = fmaf(w0, f0.w, a3);
        a0 = fmaf(w1, f1.x, a0); a1 = fmaf(w1, f1.y, a1);
        a2 = fmaf(w1, f1.z, a2); a3 = fmaf(w1, f1.w, a3);
        a0 = fmaf(w2, f2.x, a0); a1 = fmaf(w2, f2.y, a1);
        a2 = fmaf(w2, f2.z, a2); a3 = fmaf(w2, f2.w, a3);
        a0 = fmaf(w3, f3.x, a0); a1 = fmaf(w3, f3.y, a1);
        a2 = fmaf(w3, f3.z, a2); a3 = fmaf(w3, f3.w, a3);
    }
    for (; i < n; ++i) {
        int s0 = sp[i];
        float w0 = WSEP ? wp[i] : w_num[s0];
        float4 f0 = ldrow4<IN_BF>(feat, s0, c);
        a0 = fmaf(w0, f0.x, a0); a1 = fmaf(w0, f0.y, a1);
        a2 = fmaf(w0, f0.z, a2); a3 = fmaf(w0, f0.w, a3);
    }
    a0 *= inv; a1 *= inv; a2 *= inv; a3 *= inv;
    if constexpr (BR) {
        float4 bv = *reinterpret_cast<const float4*>(bias + c);
        a0 = fmaxf(a0 + bv.x, 0.f); a1 = fmaxf(a1 + bv.y, 0.f);
        a2 = fmaxf(a2 + bv.z, 0.f); a3 = fmaxf(a3 + bv.w, 0.f);
    }
    if constexpr (OUT_BF) {
        us4 o = { f2bf(a0), f2bf(a1), f2bf(a2), f2bf(a3) };
        *reinterpret_cast<us4*>((unsigned short*)out + (size_t)row * D + c) = o;
    } else {
        float4 o = make_float4(a0, a1, a2, a3);
        *reinterpret_cast<float4*>((float*)out + (size_t)row * D + c) = o;
    }
}

// ---------------------------------------------------------------------------
// Tier-A gather: 16 lanes/row, 16 rows/block, branchless padded 4-way loop.
// ---------------------------------------------------------------------------
template <int OUT_BF, int BR>
__global__ void __launch_bounds__(256) gather16_kernel(
    const unsigned short* __restrict__ feat,   // [n_src, D] bf16
    const float* __restrict__ w_den,           // [n_dst]
    const int*   __restrict__ sorted_src,      // [I] grouped by dst
    const float* __restrict__ sorted_w,        // [I] pre-gathered weights
    const int*   __restrict__ off,             // [n_dst] absolute starts
    const int*   __restrict__ cnt,             // [n_dst] lengths
    const float* __restrict__ bias,
    void* __restrict__ out, int n_dst, int n_src)
{
    int row = blockIdx.x * 16 + (threadIdx.x >> 4);
    if (row >= n_dst) return;
    int c = (threadIdx.x & 15) << 3;    // 8 elems per lane
    int start = off[row];
    const int* sp = sorted_src + start;
    const float* wp = sorted_w + start;
    int n = cnt[row];
    const int smax = n_src - 1;
    float inv = 1.0f / w_den[row];
    float a[8];
    #pragma unroll
    for (int j = 0; j < 8; ++j) a[j] = 0.f;
    for (int i = 0; i < n; i += 4) {
        int s0 = min(sp[i], smax);
        int s1 = min(sp[i + 1], smax);
        int s2 = min(sp[i + 2], smax);
        int s3 = min(sp[i + 3], smax);
        float w0 = wp[i];
        float w1 = (i + 1 < n) ? wp[i + 1] : 0.f;
        float w2 = (i + 2 < n) ? wp[i + 2] : 0.f;
        float w3 = (i + 3 < n) ? wp[i + 3] : 0.f;
        us8 f0 = *reinterpret_cast<const us8*>(feat + (size_t)s0 * D + c);
        us8 f1 = *reinterpret_cast<const us8*>(feat + (size_t)s1 * D + c);
        us8 f2 = *reinterpret_cast<const us8*>(feat + (size_t)s2 * D + c);
        us8 f3 = *reinterpret_cast<const us8*>(feat + (size_t)s3 * D + c);
        #pragma unroll
        for (int j = 0; j < 8; ++j) a[j] = fmaf(w0, bf2f(f0[j]), a[j]);
        #pragma unroll
        for (int j = 0; j < 8; ++j) a[j] = fmaf(w1, bf2f(f1[j]), a[j]);
        #pragma unroll
        for (int j = 0; j < 8; ++j) a[j] = fmaf(w2, bf2f(f2[j]), a[j]);
        #pragma unroll
        for (int j = 0; j < 8; ++j) a[j] = fmaf(w3, bf2f(f3[j]), a[j]);
    }
    #pragma unroll
    for (int j = 0; j < 8; ++j) a[j] *= inv;
    if constexpr (BR) {
        float4 bv0 = *reinterpret_cast<const float4*>(bias + c);
        float4 bv1 = *reinterpret_cast<const float4*>(bias + c + 4);
        a[0] = fmaxf(a[0] + bv0.x, 0.f); a[1] = fmaxf(a[1] + bv0.y, 0.f);
        a[2] = fmaxf(a[2] + bv0.z, 0.f); a[3] = fmaxf(a[3] + bv0.w, 0.f);
        a[4] = fmaxf(a[4] + bv1.x, 0.f); a[5] = fmaxf(a[5] + bv1.y, 0.f);
        a[6] = fmaxf(a[6] + bv1.z, 0.f); a[7] = fmaxf(a[7] + bv1.w, 0.f);
    }
    if constexpr (OUT_BF) {
        us8 o = { f2bf(a[0]), f2bf(a[1]), f2bf(a[2]), f2bf(a[3]),
                  f2bf(a[4]), f2bf(a[5]), f2bf(a[6]), f2bf(a[7]) };
        *reinterpret_cast<us8*>((unsigned short*)out + (size_t)row * D + c) = o;
    } else {
        float* op = (float*)out + (size_t)row * D + c;
        *reinterpret_cast<float4*>(op)     = make_float4(a[0], a[1], a[2], a[3]);
        *reinterpret_cast<float4*>(op + 4) = make_float4(a[4], a[5], a[6], a[7]);
    }
}

// ---------------------------------------------------------------------------
// LDS staging helpers for MFMA GEMMs. NT = thread count.
// ---------------------------------------------------------------------------
template <int NT, int ROWS>
__device__ __forceinline__ void stage_A(
    unsigned short* A_lds, const float* __restrict__ in, int r0, int nrows, int tid)
{
    #pragma unroll
    for (int it = 0; it < ROWS * 32 / NT; ++it) {
        int e   = tid + it * NT;
        int row = e >> 5;
        int c4  = (e & 31) << 2;
        int grow = r0 + row;
        float4 v = make_float4(0.f, 0.f, 0.f, 0.f);
        if (grow < nrows)
            v = *reinterpret_cast<const float4*>(in + (size_t)grow * D + c4);
        us4 b = { f2bf(v.x), f2bf(v.y), f2bf(v.z), f2bf(v.w) };
        *reinterpret_cast<us4*>(A_lds + row * LDSP + c4) = b;
    }
}

template <int NT, int ROWS>
__device__ __forceinline__ void stage_A_bf(
    unsigned short* A_lds, const unsigned short* __restrict__ in,
    int r0, int nrows, int tid)
{
    #pragma unroll
    for (int it = 0; it < ROWS * 16 / NT; ++it) {
        int e   = tid + it * NT;
        int row = e >> 4;
        int c8  = (e & 15) << 3;
        int grow = r0 + row;
        bf16x8 v;
        #pragma unroll
        for (int j = 0; j < 8; ++j) v[j] = 0;
        if (grow < nrows)
            v = *reinterpret_cast<const bf16x8*>(in + (size_t)grow * D + c8);
        *reinterpret_cast<bf16x8*>(A_lds + row * LDSP + c8) = v;
    }
}

template <int NT>
__device__ __forceinline__ void stage_Wt(
    unsigned short* W_lds, const float* __restrict__ W, int tid)
{
    #pragma unroll
    for (int it = 0; it < D * 32 / NT; ++it) {
        int e   = tid + it * NT;
        int row = e >> 5;
        int c4  = (e & 31) << 2;
        float4 v = *reinterpret_cast<const float4*>(W + (size_t)row * D + c4);
        us4 b = { f2bf(v.x), f2bf(v.y), f2bf(v.z), f2bf(v.w) };
        *reinterpret_cast<us4*>(W_lds + row * LDSP + c4) = b;
    }
}

__device__ __forceinline__ void mfma_16x128(
    const unsigned short* A_lds, const unsigned short* W_lds,
    int wv, int lane, f32x4 acc[8])
{
    const int lr = lane & 15;
    const int lk = (lane >> 4) << 3;
    const unsigned short* arow = A_lds + (wv * 16 + lr) * LDSP;
    #pragma unroll
    for (int kt = 0; kt < 4; ++kt) {
        bf16x8 af = *reinterpret_cast<const bf16x8*>(arow + kt * 32 + lk);
        #pragma unroll
        for (int ct = 0; ct < 8; ++ct) {
            bf16x8 bfr = *reinterpret_cast<const bf16x8*>(
                W_lds + (ct * 16 + lr) * LDSP + kt * 32 + lk);
            acc[ct] = __builtin_amdgcn_mfma_f32_16x16x32_bf16(af, bfr, acc[ct], 0, 0, 0);
        }
    }
}

template <int MODE>
__global__ void __launch_bounds__(256) mfma_gemm_kernel(
    const float* __restrict__ in, const float* __restrict__ W,
    const float* __restrict__ bias, float* __restrict__ out, int nrows)
{
    __shared__ unsigned short A_lds[64 * LDSP];
    __shared__ unsigned short W_lds[D * LDSP];

    const int tid  = threadIdx.x;
    const int r0   = blockIdx.x * 64;
    const int wv   = tid >> 6;
    const int lane = tid & 63;

    stage_A<256, 64>(A_lds, in, r0, nrows, tid);
    stage_Wt<256>(W_lds, W, tid);
    __syncthreads();

    f32x4 acc[8];
    #pragma unroll
    for (int ct = 0; ct < 8; ++ct) acc[ct] = (f32x4){0.f, 0.f, 0.f, 0.f};
    mfma_16x128(A_lds, W_lds, wv, lane, acc);

    const int lr = lane & 15;
    const int rb = r0 + wv * 16 + ((lane >> 4) << 2);
    #pragma unroll
    for (int ct = 0; ct < 8; ++ct) {
        int col = ct * 16 + lr;
        float bv = bias[col];
        #pragma unroll
        for (int i = 0; i < 4; ++i) {
            int row = rb + i;
            if (row >= nrows) continue;
            float x = acc[ct][i] + bv;
            if (MODE == 2) x = fmaxf(x, 0.f);
            out[(size_t)row * D + col] = x;
        }
    }
}

template <int RBF>
__global__ void __launch_bounds__(256) mfma_dualgemm_kernel(
    const float* __restrict__ inL, const float* __restrict__ WL,
    const float* __restrict__ bL,
    const void*  __restrict__ inR, const float* __restrict__ WR,
    const float* __restrict__ bR,
    float* __restrict__ out, int nrows)
{
    __shared__ unsigned short A_lds[64 * LDSP];
    __shared__ unsigned short W_lds[D * LDSP];

    const int tid  = threadIdx.x;
    const int r0   = blockIdx.x * 64;
    const int wv   = tid >> 6;
    const int lane = tid & 63;

    f32x4 acc0[8], acc1[8];
    #pragma unroll
    for (int ct = 0; ct < 8; ++ct) {
        acc0[ct] = (f32x4){0.f, 0.f, 0.f, 0.f};
        acc1[ct] = (f32x4){0.f, 0.f, 0.f, 0.f};
    }

    stage_A<256, 64>(A_lds, inL, r0, nrows, tid);
    stage_Wt<256>(W_lds, WL, tid);
    __syncthreads();
    mfma_16x128(A_lds, W_lds, wv, lane, acc0);
    __syncthreads();

    if constexpr (RBF)
        stage_A_bf<256, 64>(A_lds, (const unsigned short*)inR, r0, nrows, tid);
    else
        stage_A<256, 64>(A_lds, (const float*)inR, r0, nrows, tid);
    stage_Wt<256>(W_lds, WR, tid);
    __syncthreads();
    mfma_16x128(A_lds, W_lds, wv, lane, acc1);

    const int lr = lane & 15;
    const int rb = r0 + wv * 16 + ((lane >> 4) << 2);
    #pragma unroll
    for (int ct = 0; ct < 8; ++ct) {
        int col = ct * 16 + lr;
        float bvL = bL[col];
        float bvR = bR[col];
        #pragma unroll
        for (int i = 0; i < 4; ++i) {
            int row = rb + i;
            if (row >= nrows) continue;
            float x = (acc0[ct][i] + bvL) + fmaxf(acc1[ct][i] + bvR, 0.f);
            out[(size_t)row * D + col] = x;
        }
    }
}

// ---------------------------------------------------------------------------
// TRIPLE GEMM (tier A), 512 threads / 128-row tile:
//   eout = (inL @ WL^T + bL) + relu(inR_bf @ WR^T + bR)   -> outE (f32)
//   Z    = eout @ WZ^T                                     -> outZ (bf16)
// ---------------------------------------------------------------------------
#define TROWS 128
__global__ void __launch_bounds__(512) mfma_trigemm_kernel(
    const float* __restrict__ inL, const float* __restrict__ WL,
    const float* __restrict__ bL,
    const unsigned short* __restrict__ inR, const float* __restrict__ WR,
    const float* __restrict__ bR,
    const float* __restrict__ WZ,
    float* __restrict__ outE, unsigned short* __restrict__ outZ, int nrows)
{
    __shared__ unsigned short A_lds[TROWS * LDSP];
    __shared__ unsigned short W_lds[D * LDSP];

    const int tid  = threadIdx.x;
    const int r0   = blockIdx.x * TROWS;
    const int wv   = tid >> 6;          // 0..7
    const int lane = tid & 63;
    const int lr   = lane & 15;
    const int lg   = lane >> 4;
    const int rb   = r0 + wv * 16 + (lg << 2);

    f32x4 acc0[8], acc1[8];
    #pragma unroll
    for (int ct = 0; ct < 8; ++ct) {
        acc0[ct] = (f32x4){0.f, 0.f, 0.f, 0.f};
        acc1[ct] = (f32x4){0.f, 0.f, 0.f, 0.f};
    }

    // pass 0: L = efeat (f32) x W_ef
    stage_A<512, TROWS>(A_lds, inL, r0, nrows, tid);
    stage_Wt<512>(W_lds, WL, tid);
    __syncthreads();
    mfma_16x128(A_lds, W_lds, wv, lane, acc0);
    __syncthreads();

    // pass 1: R = acc_e (bf16) x W_ve
    stage_A_bf<512, TROWS>(A_lds, inR, r0, nrows, tid);
    stage_Wt<512>(W_lds, WR, tid);
    __syncthreads();
    mfma_16x128(A_lds, W_lds, wv, lane, acc1);

    // epilogue 1: acc0 <- eout = (acc0+bL) + relu(acc1+bR); store f32
    #pragma unroll
    for (int ct = 0; ct < 8; ++ct) {
        int col = ct * 16 + lr;
        float bvL = bL[col];
        float bvR = bR[col];
        #pragma unroll
        for (int i = 0; i < 4; ++i) {
            float x = (acc0[ct][i] + bvL) + fmaxf(acc1[ct][i] + bvR, 0.f);
            acc0[ct][i] = x;
            int row = rb + i;
            if (row < nrows) outE[(size_t)row * D + col] = x;
        }
    }

    __syncthreads();   // all pass-1 LDS reads done before restage

    // restage eout tile (bf16): each wave fills its own 16-row slab
    #pragma unroll
    for (int ct = 0; ct < 8; ++ct) {
        int col = ct * 16 + lr;
        #pragma unroll
        for (int i = 0; i < 4; ++i) {
            A_lds[(wv * 16 + (lg << 2) + i) * LDSP + col] = f2bf(acc0[ct][i]);
        }
    }
    stage_Wt<512>(W_lds, WZ, tid);
    __syncthreads();

    // pass 2: Z = eout x W_ev  (acc1 reused)
    #pragma unroll
    for (int ct = 0; ct < 8; ++ct) acc1[ct] = (f32x4){0.f, 0.f, 0.f, 0.f};
    mfma_16x128(A_lds, W_lds, wv, lane, acc1);

    #pragma unroll
    for (int ct = 0; ct < 8; ++ct) {
        int col = ct * 16 + lr;
        #pragma unroll
        for (int i = 0; i < 4; ++i) {
            int row = rb + i;
            if (row < nrows) outZ[(size_t)row * D + col] = f2bf(acc1[ct][i]);
        }
    }
}

// ---------------------------------------------------------------------------
extern "C" void kernel_launch(void* const* d_in, const int* in_sizes, int n_in,
                              void* d_out, int out_size, void* d_ws, size_t ws_size,
                              hipStream_t stream)
{
    const float* vfeat = (const float*)d_in[0];
    const float* efeat = (const float*)d_in[1];
    const float* vrw   = (const float*)d_in[2];
    const float* vrs   = (const float*)d_in[3];
    const float* erw   = (const float*)d_in[4];
    const float* ers   = (const float*)d_in[5];
    const float* W_ve  = (const float*)d_in[6];
    const float* b_ve  = (const float*)d_in[7];
    const float* W_ev  = (const float*)d_in[8];
    const float* b_ev  = (const float*)d_in[9];
    const float* W_ef  = (const float*)d_in[10];
    const float* b_ef  = (const float*)d_in[11];
    const int* node_idx = (const int*)d_in[12];
    const int* edge_idx = (const int*)d_in[13];

    const int V = in_sizes[0] / D;   // 100000
    const int E = in_sizes[1] / D;   // 40000
    const int I = in_sizes[12];      // 600000
    const int EV = E + V;

    float* vfeat_out = (float*)d_out;                  // [V, D]
    float* efeat_out = (float*)d_out + (size_t)V * D;  // [E, D]

    const int NBE = (E + 63) >> 6;    // 625 edge buckets (64 bins each)
    const int NBV = (V + 127) >> 7;   // 782 node buckets (128 bins each)
    const int HB  = (I + PART_ELEMS - 1) / PART_ELEMS;  // 147

    // ---- tier-A workspace layout (no gCnt; atomic-free build) ----
    int* bktBaseE   = (int*)d_ws;                 // [NBE+1]
    int* bktBaseV   = bktBaseE + NBE + 1;         // [NBV+1]
    int* blockBaseE = bktBaseV + NBV + 1;         // [HB*NBE]
    int* blockBaseV = blockBaseE + (size_t)HB * NBE; // [HB*NBV]
    int* offE       = blockBaseV + (size_t)HB * NBV; // [E]
    int* cntE       = offE + E;                   // [E]
    int* offV       = cntE + E;                   // [V]
    int* cntV       = offV + V;                   // [V]
    int* sorted_n   = cntV + V;                   // [I]
    int* sorted_e   = sorted_n + I;               // [I]
    float* sorted_wn = (float*)(sorted_e + I);    // [I] pre-gathered vrw
    float* sorted_we = sorted_wn + I;             // [I] pre-gathered erw
    size_t fixed_ints = (size_t)((int*)(sorted_we + I) - (int*)d_ws);
    fixed_ints = (fixed_ints + 3) & ~(size_t)3;   // 16B-align the union region
    // union region: pairsE/pairsV (2I ints, dead after bin_csr)  vs  z_bf
    int* pairsE = (int*)d_ws + fixed_ints;
    int* pairsV = pairsE + I;
    unsigned short* z_bf = (unsigned short*)pairsE;   // [E*D] born at trigemm
    size_t union_bytes = (size_t)2 * I * 4;
    if ((size_t)E * D * 2 > union_bytes) union_bytes = (size_t)E * D * 2;
    size_t ws_needA = fixed_ints * 4 + union_bytes + 64;  // +64: gather over-read pad

    // old tier-B layout (f32 gathers, bsum-folded)
    size_t ws_needB = ((size_t)2 * EV + 64 + (size_t)4 * I) * sizeof(int);

    if (ws_size >= ws_needA && NBE <= 1024 && NBV <= 1024) {
        // ======== tier A: bucketed CSR + bf16 gathers + fused triple GEMM ====
        unsigned short* vfeat_bf = (unsigned short*)d_out;       // [V*D]
        unsigned short* acc_e_bf = vfeat_bf + (size_t)V * D;     // [E*D]
        // 25.6 + 10.2 MB <= 51.2 MB f32 region; dead before gather2 writes.

        part_hist_kernel<<<HB, 1024, 0, stream>>>(
            node_idx, edge_idx, blockBaseE, blockBaseV, NBE, NBV, I);
        // fat dispatch: blocks 0/1 scan, blocks 2.. convert vfeat -> bf16
        fat_scan_cvt_kernel<<<2 + 512, 1024, 0, stream>>>(
            blockBaseE, bktBaseE, NBE, blockBaseV, bktBaseV, NBV, HB,
            vfeat, vfeat_bf, V * D / 4);
        part_scatter_kernel<<<HB, 1024, 0, stream>>>(
            node_idx, edge_idx, bktBaseE, bktBaseV, blockBaseE, blockBaseV,
            pairsE, pairsV, NBE, NBV, I);
        bin_csr_kernel<<<NBE + NBV, 256, 0, stream>>>(
            pairsE, pairsV, bktBaseE, bktBaseV,
            offE, cntE, offV, cntV, sorted_n, sorted_e,
            vrw, erw, sorted_wn, sorted_we, NBE, NBV, E, V);

        // g1: nodes -> hyperedges (bf16 table, bf16 out, padded 16 lanes/row)
        gather16_kernel<1, 0><<<(E + 15) / 16, 256, 0, stream>>>(
            vfeat_bf, ers, sorted_n, sorted_wn, offE, cntE, nullptr,
            acc_e_bf, E, V);

        // eout = (efeat@W_ef^T+b_ef) + relu(acc_e@W_ve^T+b_ve);  Z = eout@W_ev^T
        mfma_trigemm_kernel<<<(E + TROWS - 1) / TROWS, 512, 0, stream>>>(
            efeat, W_ef, b_ef, acc_e_bf, W_ve, b_ve, W_ev, efeat_out, z_bf, E);

        // g2: vfeat_out = relu( (sum w * Z[e]) / vrs + b_ev )
        gather16_kernel<0, 1><<<(V + 15) / 16, 256, 0, stream>>>(
            z_bf, vrs, sorted_e, sorted_we, offV, cntV, b_ev,
            vfeat_out, V, E);
    } else if (ws_size >= ws_needB) {
        // ======== tier B: old atomic hist + place, f32 gathers ========
        int* cnt_cat  = (int*)d_ws;
        int* off_cat  = cnt_cat + EV;
        int* bsum     = off_cat + EV;
        int* rank_e   = bsum + 64;
        int* rank_v   = rank_e + I;
        int* sorted_nb = rank_v + I;
        int* sorted_eb = sorted_nb + I;
        const int inc_blocks  = (I + 255) / 256;
        const int half_blocks = (((I + 1) >> 1) + 255) / 256;
        const int nb = (EV + SCAN_CHUNK - 1) / SCAN_CHUNK;
        float* acc_e = vfeat_out;

        hipMemsetAsync(cnt_cat, 0, (size_t)EV * sizeof(int), stream);
        hist_rank_kernel<<<half_blocks, 256, 0, stream>>>(
            node_idx, edge_idx, cnt_cat, rank_e, rank_v, E, I);
        scan_block_kernel<<<nb, 1024, 0, stream>>>(cnt_cat, off_cat, bsum, EV);
        scan_block_kernel<<<1, 1024, 0, stream>>>(bsum, bsum, nullptr, nb);
        place_kernel<<<inc_blocks, 256, 0, stream>>>(
            node_idx, edge_idx, rank_e, rank_v, off_cat, bsum, sorted_nb, sorted_eb, E, I);
        gather_seg_kernel<0, 0, 0, 0><<<(E + 7) / 8, 256, 0, stream>>>(
            vfeat, vrw, ers, sorted_nb, nullptr, off_cat, bsum, cnt_cat, 0, 0,
            nullptr, acc_e, E);
        mfma_dualgemm_kernel<0><<<(E + 63) / 64, 256, 0, stream>>>(
            efeat, W_ef, b_ef, acc_e, W_ve, b_ve, efeat_out, E);
        gather_seg_kernel<0, 0, 0, 0><<<(V + 7) / 8, 256, 0, stream>>>(
            efeat_out, erw, vrs, sorted_eb, nullptr, off_cat, bsum, cnt_cat, E, -I,
            nullptr, vfeat_out, V);
        mfma_gemm_kernel<2><<<(V + 63) / 64, 256, 0, stream>>>(
            vfeat_out, W_ev, b_ev, vfeat_out, V);
    } else {
        // ======== tier C: atomic fallback ========
        float* acc_e = vfeat_out;
        const int sb = (I * 32 + 255) / 256;
        hipMemsetAsync(acc_e, 0, (size_t)E * D * sizeof(float), stream);
        scatter_kernel<<<sb, 256, 0, stream>>>(vfeat, vrw, ers, node_idx, edge_idx, acc_e, I);
        mfma_dualgemm_kernel<0><<<(E + 63) / 64, 256, 0, stream>>>(
            efeat, W_ef, b_ef, acc_e, W_ve, b_ve, efeat_out, E);
        hipMemsetAsync(vfeat_out, 0, (size_t)V * D * sizeof(float), stream);
        scatter_kernel<<<sb, 256, 0, stream>>>(efeat_out, erw, vrs, edge_idx, node_idx, vfeat_out, I);
        mfma_gemm_kernel<2><<<(V + 63) / 64, 256, 0, stream>>>(vfeat_out, W_ev, b_ev, vfeat_out, V);
    }
}